// Round 14
// baseline (772.184 us; speedup 1.0000x reference)
//
#include <hip/hip_runtime.h>
#include <stdint.h>
#include <stddef.h>
#include <math.h>

#define HWSZ   3136        // 56*56
#define NPIX   100352      // 32*3136

typedef __attribute__((ext_vector_type(4))) float f32x4;
typedef __attribute__((ext_vector_type(8))) short bf16x8;
typedef __attribute__((ext_vector_type(8))) unsigned short u16x8;

__device__ __forceinline__ float bf2f(unsigned short u) {
  union { float f; unsigned int i; } v; v.i = ((unsigned int)u) << 16; return v.f;
}
__device__ __forceinline__ unsigned short f2bf(float f) {
  union { float f; unsigned int i; } v; v.f = f;
  return (unsigned short)((v.i + 0x7FFFu + ((v.i >> 16) & 1u)) >> 16);
}
__device__ __forceinline__ unsigned short sgnf_bf16(float v) {
  return (v > 0.f) ? 0x3F80u : ((v < 0.f) ? 0xBF80u : 0u);
}
__device__ __forceinline__ int isgn(float v) {
  return (v > 0.f) ? 1 : ((v < 0.f) ? -1 : 0);
}

// ---------------------------------------------------------------------------
// K0: weight prep: sign(w) as bf16, [o][c] layout
// ---------------------------------------------------------------------------
__global__ __launch_bounds__(256) void k_prepw(const float* __restrict__ w1,
    const float* __restrict__ w2, const float* __restrict__ w3,
    unsigned short* __restrict__ bs)
{
  int idx = blockIdx.x * 256 + threadIdx.x;
  int wsel = idx >> 16, rem = idx & 65535;
  const float* wp = (wsel == 0) ? w1 : ((wsel == 1) ? w2 : w3);
  float v = wp[rem];
  bs[idx] = sgnf_bf16(v);
}

// ---------------------------------------------------------------------------
// K1: depthwise 3x3 sign-conv -> c1 int8 + fused plane mean-partials.
// ---------------------------------------------------------------------------
__global__ __launch_bounds__(256) void k_dwconv(const float* __restrict__ x,
    const float* __restrict__ wdw, const float* __restrict__ a1,
    signed char* __restrict__ c1, float* __restrict__ P1)
{
  __shared__ float sp[58 * 60];    // row r = h+1, col = w+2
  __shared__ float rs[4];
  int bid = blockIdx.x;            // n*256 + c
  int c = bid & 255;
  int t = threadIdx.x;
  const float* xp = x + (size_t)bid * HWSZ;

  for (int i = t; i < 58 * 60; i += 256) sp[i] = 0.f;
  __syncthreads();
  for (int q = t; q < 784; q += 256) {
    int h = q / 14, w0 = (q - h * 14) * 4;
    f32x4 v = *(const f32x4*)(xp + h * 56 + w0);
    float* d = sp + (h + 1) * 60 + (w0 + 2);
    d[0] = (float)isgn(v[0]);
    d[1] = (float)isgn(v[1]);
    d[2] = (float)isgn(v[2]);
    d[3] = (float)isgn(v[3]);
  }
  float wsf[9];
  #pragma unroll
  for (int i = 0; i < 9; i++) wsf[i] = (float)isgn(wdw[c * 9 + i]);
  float av = a1[c];
  __syncthreads();

  float lsum = 0.f;
  signed char* outp = c1 + (size_t)bid * HWSZ;
  for (int q = t; q < 784; q += 256) {
    int h = q / 14, w0 = (q - h * 14) * 4;
    float win[3][8];
    #pragma unroll
    for (int r = 0; r < 3; r++) {
      const float* rowp = sp + (h + r) * 60 + w0;
      *(f32x4*)(&win[r][0]) = *(const f32x4*)rowp;
      *(f32x4*)(&win[r][4]) = *(const f32x4*)(rowp + 4);
    }
    unsigned int pk = 0;
    #pragma unroll
    for (int j = 0; j < 4; j++) {
      float acc = 0.f;
      #pragma unroll
      for (int r = 0; r < 3; r++) {
        acc = fmaf(win[r][j + 1], wsf[r * 3 + 0], acc);
        acc = fmaf(win[r][j + 2], wsf[r * 3 + 1], acc);
        acc = fmaf(win[r][j + 3], wsf[r * 3 + 2], acc);
      }
      int ia = (int)acc;
      pk |= ((unsigned int)(unsigned char)(signed char)ia) << (8 * j);
      lsum += (acc >= 0.f) ? acc : av * acc;       // exact quarter-ints
    }
    *(unsigned int*)(void*)(outp + h * 56 + w0) = pk;
  }
  for (int o = 32; o > 0; o >>= 1) lsum += __shfl_xor(lsum, o);
  if ((t & 63) == 0) rs[t >> 6] = lsum;
  __syncthreads();
  if (t == 0) P1[bid] = ((rs[0] + rs[1]) + (rs[2] + rs[3]));
}

// mean combine (layer1): seq over 32 plane sums (exact), /100352 f32
__global__ __launch_bounds__(256) void k_cmb(const float* __restrict__ P,
    float* __restrict__ M)
{
  int c = threadIdx.x;
  float acc = 0.f;
  for (int n = 0; n < 32; n++) acc = __fadd_rn(acc, P[n * 256 + c]);
  M[c] = __fdiv_rn(acc, 100352.0f);
}

// mean combine (gemm layers): seq over 784 block partials (exact)
__global__ __launch_bounds__(256) void k_cmbG(const float* __restrict__ PM,
    float* __restrict__ M)
{
  int c = threadIdx.x;
  float acc = 0.f;
  for (int b = 0; b < 784; b++) acc = __fadd_rn(acc, PM[(size_t)b * 256 + c]);
  M[c] = __fdiv_rn(acc, 100352.0f);
}

// ===========================================================================
// VARIANCE — bit-exact numpy float32 pairwise order, parallelized.
// ===========================================================================

// var1: one block per (n,c) plane (NCHW int8); 256 thr = 32 leaves x 8 accs
__global__ __launch_bounds__(256) void k_var1(const signed char* __restrict__ c1,
    const float* __restrict__ a1, const float* __restrict__ M,
    float* __restrict__ PV)
{
  __shared__ float rr[256];
  __shared__ float lsm[32];
  int bid = blockIdx.x;
  int c = bid & 255;
  int t = threadIdx.x;
  int lf = t >> 3, j = t & 7;
  const int base = (lf >> 2) * 392 + (lf & 3) * 96;
  const int nb = ((lf & 3) == 3) ? 13 : 12;
  const signed char* pl = c1 + (size_t)bid * HWSZ + base + j;
  float av = a1[c], m = M[c];
  float r;
  {
    float v = (float)(int)pl[0];
    float tt = (v >= 0.f) ? v : __fmul_rn(av, v);
    float d = __fsub_rn(tt, m);
    r = __fmul_rn(d, d);
  }
  for (int b = 1; b < nb; b++) {
    float v = (float)(int)pl[8 * b];
    float tt = (v >= 0.f) ? v : __fmul_rn(av, v);
    float d = __fsub_rn(tt, m);
    r = __fadd_rn(r, __fmul_rn(d, d));
  }
  rr[t] = r;
  __syncthreads();
  if (j == 0) {
    const float* q = rr + lf * 8;
    lsm[lf] = __fadd_rn(
        __fadd_rn(__fadd_rn(q[0], q[1]), __fadd_rn(q[2], q[3])),
        __fadd_rn(__fadd_rn(q[4], q[5]), __fadd_rn(q[6], q[7])));
  }
  __syncthreads();
  if (t == 0) {
    float ch[8];
    #pragma unroll
    for (int q8 = 0; q8 < 8; q8++)
      ch[q8] = __fadd_rn(__fadd_rn(lsm[q8 * 4], lsm[q8 * 4 + 1]),
                         __fadd_rn(lsm[q8 * 4 + 2], lsm[q8 * 4 + 3]));
    float s0 = __fadd_rn(ch[0], ch[1]), s1 = __fadd_rn(ch[2], ch[3]);
    float s2 = __fadd_rn(ch[4], ch[5]), s3 = __fadd_rn(ch[6], ch[7]);
    PV[bid] = __fadd_rn(__fadd_rn(s0, s1), __fadd_rn(s2, s3));
  }
}

// var combine (layer1): seq over n plane sums, /100352, CR f32 rsqrt
__global__ __launch_bounds__(256) void k_vcmb(const float* __restrict__ PV,
    float* __restrict__ R)
{
  int c = threadIdx.x;
  float acc = 0.f;
  for (int n = 0; n < 32; n++) acc = __fadd_rn(acc, PV[n * 256 + c]);
  float v = __fdiv_rn(acc, 100352.0f);
  R[c] = (float)(1.0 / sqrt((double)__fadd_rn(v, 1e-5f)));
}

// varT: one block per (n, leaf) (NHWC bf16); 256 thr = 256 channels
__global__ __launch_bounds__(256) void k_varT(const unsigned short* __restrict__ tb,
    const float* __restrict__ M, float* __restrict__ PVL)
{
  int n = blockIdx.x >> 5, lf = blockIdx.x & 31;
  int c = threadIdx.x;
  const int base = (lf >> 2) * 392 + (lf & 3) * 96;
  const int nb = ((lf & 3) == 3) ? 13 : 12;
  const unsigned short* pl = tb + ((size_t)n * HWSZ + base) * 256 + c;
  float m = M[c];
  float r[8];
  #pragma unroll
  for (int j = 0; j < 8; j++) {
    float d = __fsub_rn(bf2f(pl[(size_t)j * 256]), m);
    r[j] = __fmul_rn(d, d);
  }
  for (int b = 1; b < nb; b++) {
    #pragma unroll
    for (int j = 0; j < 8; j++) {
      float d = __fsub_rn(bf2f(pl[(size_t)(8 * b + j) * 256]), m);
      r[j] = __fadd_rn(r[j], __fmul_rn(d, d));
    }
  }
  float lv = __fadd_rn(
      __fadd_rn(__fadd_rn(r[0], r[1]), __fadd_rn(r[2], r[3])),
      __fadd_rn(__fadd_rn(r[4], r[5]), __fadd_rn(r[6], r[7])));
  PVL[(size_t)blockIdx.x * 256 + c] = lv;
}

// varT combine: exact tree over 32 leaves, seq over n, /100352, CR rsqrt
__global__ __launch_bounds__(256) void k_vcmbT(const float* __restrict__ PVL,
    float* __restrict__ R)
{
  int c = threadIdx.x;
  float acc = 0.f;
  for (int n = 0; n < 32; n++) {
    float ch[8];
    #pragma unroll
    for (int q = 0; q < 8; q++) {
      const float* p = PVL + ((size_t)(n * 32 + q * 4)) * 256 + c;
      ch[q] = __fadd_rn(__fadd_rn(p[0], p[256]), __fadd_rn(p[512], p[768]));
    }
    float s0 = __fadd_rn(ch[0], ch[1]), s1 = __fadd_rn(ch[2], ch[3]);
    float s2 = __fadd_rn(ch[4], ch[5]), s3 = __fadd_rn(ch[6], ch[7]);
    float plane = __fadd_rn(__fadd_rn(s0, s1), __fadd_rn(s2, s3));
    acc = __fadd_rn(acc, plane);
  }
  float v = __fdiv_rn(acc, 100352.0f);
  R[c] = (float)(1.0 / sqrt((double)__fadd_rn(v, 1e-5f)));
}

// ---------------------------------------------------------------------------
// K2: apply1: SB = sign( ((t1-m)*r)*g + b + x ). 4 px/thread, vectorized
// f32x4 x-loads + uint c1-loads; XOR block-swizzled LDS staging.
// ---------------------------------------------------------------------------
__global__ __launch_bounds__(256) void k_apply1(const float* __restrict__ x,
    const signed char* __restrict__ c1, const float* __restrict__ a1,
    const float* __restrict__ M1, const float* __restrict__ R1,
    const float* __restrict__ g1, const float* __restrict__ b1,
    unsigned short* __restrict__ s1)
{
  __shared__ __align__(16) unsigned short lb[32 * 264];
  int bid = blockIdx.x;
  int n = bid / 98, pb = bid % 98;
  int px0 = pb * 32;
  int t = threadIdx.x;

  int pxg = (t & 7) * 4, cb = t >> 3;
  #pragma unroll
  for (int j = 0; j < 8; j++) {
    int c = cb + j * 32;
    size_t gidx = ((size_t)(n * 256 + c)) * HWSZ + px0 + pxg;
    f32x4 xv = *(const f32x4*)(x + gidx);
    unsigned int cp = *(const unsigned int*)(const void*)(c1 + gidx);
    float av = a1[c];
    float m1 = M1[c], r1 = R1[c], gg1 = g1[c], bb1 = b1[c];
    #pragma unroll
    for (int e = 0; e < 4; e++) {
      int row = pxg + e;
      int idx = row * 264 + (c ^ (((row >> 2) & 7) << 3));
      float v = (float)(int)(signed char)(unsigned char)(cp >> (8 * e));
      float t1 = (v >= 0.f) ? v : __fmul_rn(av, v);
      float xn = __fmul_rn(__fsub_rn(t1, m1), r1);
      float bn = __fadd_rn(__fmul_rn(xn, gg1), bb1);
      float o1 = __fadd_rn(bn, xv[e]);
      lb[idx] = sgnf_bf16(o1);
    }
  }
  __syncthreads();
  unsigned short* sp = s1 + ((size_t)(n * HWSZ + px0)) * 256;
  for (int j = 0; j < 4; j++) {
    int f = j * 256 + t;
    int px = f >> 5, c16 = f & 31;
    int cs = (c16 ^ ((px >> 2) & 7)) * 8;
    *(u16x8*)(sp + px * 256 + c16 * 8) = *(const u16x8*)(lb + px * 264 + cs);
  }
}

// ---------------------------------------------------------------------------
// K4: apply2: SB = sign( bn2(t2) + (bn1(t1)+x) ). In-place swizzled LDS,
// 4 px/thread vectorized x/c1 loads. Slot (px,c) read+written by same thread.
// ---------------------------------------------------------------------------
__global__ __launch_bounds__(256) void k_apply2(const float* __restrict__ x,
    const signed char* __restrict__ c1, const unsigned short* __restrict__ t2,
    const float* __restrict__ a1,
    const float* __restrict__ M1, const float* __restrict__ R1,
    const float* __restrict__ g1, const float* __restrict__ b1,
    const float* __restrict__ M2, const float* __restrict__ R2,
    const float* __restrict__ g2, const float* __restrict__ b2,
    unsigned short* __restrict__ s2)
{
  __shared__ __align__(16) unsigned short lb[32 * 264];
  int bid = blockIdx.x;
  int n = bid / 98, pb = bid % 98;
  int px0 = pb * 32;
  int t = threadIdx.x;

  const unsigned short* tp = t2 + ((size_t)(n * HWSZ + px0)) * 256;
  for (int j = 0; j < 4; j++) {
    int f = j * 256 + t;
    int px = f >> 5, c16 = f & 31;
    int cs = (c16 ^ ((px >> 2) & 7)) * 8;
    *(u16x8*)(lb + px * 264 + cs) = *(const u16x8*)(tp + px * 256 + c16 * 8);
  }
  __syncthreads();

  int pxg = (t & 7) * 4, cb = t >> 3;
  #pragma unroll
  for (int j = 0; j < 8; j++) {
    int c = cb + j * 32;
    size_t gidx = ((size_t)(n * 256 + c)) * HWSZ + px0 + pxg;
    f32x4 xv = *(const f32x4*)(x + gidx);
    unsigned int cp = *(const unsigned int*)(const void*)(c1 + gidx);
    float av = a1[c];
    float m1 = M1[c], r1 = R1[c], gg1 = g1[c], bb1 = b1[c];
    float m2 = M2[c], r2 = R2[c], gg2 = g2[c], bb2 = b2[c];
    #pragma unroll
    for (int e = 0; e < 4; e++) {
      int row = pxg + e;
      int idx = row * 264 + (c ^ (((row >> 2) & 7) << 3));
      float v = (float)(int)(signed char)(unsigned char)(cp >> (8 * e));
      float t1 = (v >= 0.f) ? v : __fmul_rn(av, v);
      float xn1 = __fmul_rn(__fsub_rn(t1, m1), r1);
      float bn1v = __fadd_rn(__fmul_rn(xn1, gg1), bb1);
      float o1 = __fadd_rn(bn1v, xv[e]);
      float t2v = bf2f(lb[idx]);
      float xn2 = __fmul_rn(__fsub_rn(t2v, m2), r2);
      float bn2v = __fadd_rn(__fmul_rn(xn2, gg2), bb2);
      float o2 = __fadd_rn(bn2v, o1);
      lb[idx] = sgnf_bf16(o2);
    }
  }
  __syncthreads();
  unsigned short* sp = s2 + ((size_t)(n * HWSZ + px0)) * 256;
  for (int j = 0; j < 4; j++) {
    int f = j * 256 + t;
    int px = f >> 5, c16 = f & 31;
    int cs = (c16 ^ ((px >> 2) & 7)) * 8;
    *(u16x8*)(sp + px * 256 + c16 * 8) = *(const u16x8*)(lb + px * 264 + cs);
  }
}

// ---------------------------------------------------------------------------
// K6: apply3: SB = sign( bn3(t3) ), f32-replica, elementwise NHWC
// ---------------------------------------------------------------------------
__global__ __launch_bounds__(256) void k_apply3(const unsigned short* __restrict__ t3,
    const float* __restrict__ M3, const float* __restrict__ R3,
    const float* __restrict__ g3, const float* __restrict__ b3,
    unsigned short* __restrict__ s3)
{
  size_t idx = ((size_t)blockIdx.x * 256 + threadIdx.x) * 8;
  int c0 = (int)(idx & 255);
  u16x8 v = *(const u16x8*)(t3 + idx);
  u16x8 o;
  #pragma unroll
  for (int e = 0; e < 8; e++) {
    int c = c0 + e;
    float t = bf2f(v[e]);
    float xn = __fmul_rn(__fsub_rn(t, M3[c]), R3[c]);
    float bn = __fadd_rn(__fmul_rn(xn, g3[c]), b3[c]);
    o[e] = sgnf_bf16(bn);
  }
  *(u16x8*)(s3 + idx) = o;
}

// ---------------------------------------------------------------------------
// K8: final: out = bn4(t4), NHWC bf16 -> NCHW fp32. 16-px tile, [px][260]
// ---------------------------------------------------------------------------
__global__ __launch_bounds__(256) void k_final(const unsigned short* __restrict__ t4,
    const float* __restrict__ M4, const float* __restrict__ R4,
    const float* __restrict__ g4, const float* __restrict__ b4,
    float* __restrict__ outp)
{
  __shared__ __align__(16) float lt[16 * 260];
  int bid = blockIdx.x;
  int n = bid / 196, pb = bid % 196;
  int px0 = pb * 16;
  int t = threadIdx.x;

  const unsigned short* tp = t4 + ((size_t)(n * HWSZ + px0)) * 256;
  for (int j = 0; j < 2; j++) {
    int f = j * 256 + t;
    int px = f >> 5, c16 = f & 31;
    u16x8 v = *(const u16x8*)(tp + px * 256 + c16 * 8);
    f32x4 o0, o1;
    #pragma unroll
    for (int e = 0; e < 4; e++) {
      int c = c16 * 8 + e;
      float tv = bf2f(v[e]);
      float xn = __fmul_rn(__fsub_rn(tv, M4[c]), R4[c]);
      o0[e] = __fadd_rn(__fmul_rn(xn, g4[c]), b4[c]);
    }
    #pragma unroll
    for (int e = 0; e < 4; e++) {
      int c = c16 * 8 + 4 + e;
      float tv = bf2f(v[4 + e]);
      float xn = __fmul_rn(__fsub_rn(tv, M4[c]), R4[c]);
      o1[e] = __fadd_rn(__fmul_rn(xn, g4[c]), b4[c]);
    }
    *(f32x4*)(lt + px * 260 + c16 * 8) = o0;
    *(f32x4*)(lt + px * 260 + c16 * 8 + 4) = o1;
  }
  __syncthreads();
  for (int j = 0; j < 4; j++) {
    int f = j * 256 + t;
    int c = f >> 2, q = f & 3;
    f32x4 v;
    #pragma unroll
    for (int e = 0; e < 4; e++) v[e] = lt[(q * 4 + e) * 260 + c];
    *(f32x4*)(outp + ((size_t)(n * 256 + c)) * HWSZ + px0 + q * 4) = v;
  }
}

// ---------------------------------------------------------------------------
// K3/5/7: GEMM: TB = prelu(SB x BS^T), exact ints via bf16 MFMA.
// XOR-swizzled LDS (48KB -> 3 blocks/CU) + LDS-staged vectorized C-write
// + fused per-block column mean-partials (exact quarter-int f32 sums).
// ---------------------------------------------------------------------------
__global__ __launch_bounds__(512, 6) void k_gemm(
    const unsigned short* __restrict__ sIn, const unsigned short* __restrict__ bsg,
    const float* __restrict__ aP, unsigned short* __restrict__ tOut,
    float* __restrict__ PM)
{
  __shared__ __align__(16) char smem[49152];
  unsigned short* As = (unsigned short*)smem;             // [128][64] swizzled
  unsigned short* Bs = (unsigned short*)(smem + 16384);   // [256][64] swizzled
  unsigned short* Cs = (unsigned short*)smem;             // [64][264] epilogue overlay
  float* red = (float*)(smem + 33792);                    // [8][32][8] (8KB)
  const int t = threadIdx.x;
  const int lane = t & 63;
  const int wid = t >> 6;
  const int wm = wid >> 2, wn = wid & 3;
  const int lr = lane & 15, lk = lane >> 4;
  const int pix0 = blockIdx.x * 128;
  const unsigned short* Ap = sIn + (size_t)pix0 * 256;

  f32x4 acc[4][4];
  #pragma unroll
  for (int i = 0; i < 4; i++)
    #pragma unroll
    for (int j = 0; j < 4; j++)
      acc[i][j] = (f32x4){0.f, 0.f, 0.f, 0.f};

  for (int kt = 0; kt < 4; kt++) {
    const int k0 = kt * 64;
    if (kt) __syncthreads();
    #pragma unroll
    for (int j = 0; j < 2; j++) {
      int idx = j * 512 + t;
      int row = idx >> 3, kc = idx & 7;
      u16x8 v = *(const u16x8*)(Ap + (size_t)row * 256 + k0 + kc * 8);
      *(u16x8*)(As + row * 64 + ((kc ^ (row & 7)) * 8)) = v;
    }
    #pragma unroll
    for (int j = 0; j < 4; j++) {
      int idx = j * 512 + t;
      int row = idx >> 3, kc = idx & 7;
      u16x8 v = *(const u16x8*)(bsg + (size_t)row * 256 + k0 + kc * 8);
      *(u16x8*)(Bs + row * 64 + ((kc ^ (row & 7)) * 8)) = v;
    }
    __syncthreads();
    #pragma unroll
    for (int h = 0; h < 2; h++) {
      bf16x8 af[4], bfr[4];
      #pragma unroll
      for (int mf = 0; mf < 4; mf++) {
        int row = wm * 64 + mf * 16 + lr;
        int ch = (h * 4 + lk) ^ (row & 7);
        af[mf] = *(const bf16x8*)(As + row * 64 + ch * 8);
      }
      #pragma unroll
      for (int nf = 0; nf < 4; nf++) {
        int nrow = wn * 64 + nf * 16 + lr;
        int ch = (h * 4 + lk) ^ (nrow & 7);
        bfr[nf] = *(const bf16x8*)(Bs + nrow * 64 + ch * 8);
      }
      #pragma unroll
      for (int mf = 0; mf < 4; mf++)
        #pragma unroll
        for (int nf = 0; nf < 4; nf++)
          acc[mf][nf] = __builtin_amdgcn_mfma_f32_16x16x32_bf16(
              af[mf], bfr[nf], acc[mf][nf], 0, 0, 0);
    }
  }

  // Epilogue: prelu -> Cs staging -> vectorized full-line stores + exact sums
  float lsum[8];
  #pragma unroll
  for (int e = 0; e < 8; e++) lsum[e] = 0.f;

  #pragma unroll
  for (int h = 0; h < 2; h++) {
    __syncthreads();
    if (wm == h) {
      #pragma unroll
      for (int nf = 0; nf < 4; nf++) {
        int col = wn * 64 + nf * 16 + lr;
        float av = aP[col];
        #pragma unroll
        for (int mf = 0; mf < 4; mf++) {
          #pragma unroll
          for (int r = 0; r < 4; r++) {
            int row = mf * 16 + lk * 4 + r;      // C/D: col=lane&15,row=(lane>>4)*4+r
            float u = acc[mf][nf][r];
            float tv = (u >= 0.f) ? u : __fmul_rn(av, u);   // exact quarter-ints
            Cs[row * 264 + col] = f2bf(tv);                 // lossless
          }
        }
      }
    }
    __syncthreads();
    #pragma unroll
    for (int j = 0; j < 4; j++) {
      int f = j * 512 + t;
      int row = f >> 5, c16 = f & 31;            // c16 == t&31, const per thread
      u16x8 v = *(const u16x8*)(Cs + row * 264 + c16 * 8);
      *(u16x8*)(tOut + ((size_t)(pix0 + h * 64 + row)) * 256 + c16 * 8) = v;
      #pragma unroll
      for (int e = 0; e < 8; e++)
        lsum[e] = __fadd_rn(lsum[e], bf2f(v[e]));           // exact, order-free
    }
  }
  #pragma unroll
  for (int e = 0; e < 8; e++)
    lsum[e] = __fadd_rn(lsum[e], __shfl_xor(lsum[e], 32));
  if (lane < 32) {
    #pragma unroll
    for (int e = 0; e < 8; e++) red[(wid * 32 + lane) * 8 + e] = lsum[e];
  }
  __syncthreads();
  if (t < 256) {
    int c16 = t >> 3, e = t & 7;
    float S = 0.f;
    #pragma unroll
    for (int w = 0; w < 8; w++)
      S = __fadd_rn(S, red[((w * 32 + c16) * 8 + e)]);
    PM[(size_t)blockIdx.x * 256 + t] = S;
  }
}

// ---------------------------------------------------------------------------
extern "C" void kernel_launch(void* const* d_in, const int* in_sizes, int n_in,
                              void* d_out, int out_size, void* d_ws, size_t ws_size,
                              hipStream_t stream)
{
  const float* x   = (const float*)d_in[0];
  const float* wdw = (const float*)d_in[1];
  const float* w1  = (const float*)d_in[2];
  const float* w2  = (const float*)d_in[3];
  const float* w3  = (const float*)d_in[4];
  const float* a1  = (const float*)d_in[5];
  const float* a2  = (const float*)d_in[6];
  const float* a3  = (const float*)d_in[7];
  const float* a4  = (const float*)d_in[8];
  const float* g1  = (const float*)d_in[9];
  const float* b1  = (const float*)d_in[10];
  const float* g2  = (const float*)d_in[11];
  const float* b2  = (const float*)d_in[12];
  const float* g3  = (const float*)d_in[13];
  const float* b3  = (const float*)d_in[14];
  const float* g4  = (const float*)d_in[15];
  const float* b4  = (const float*)d_in[16];

  char* ws = (char*)d_ws;
  unsigned short* SB  = (unsigned short*)ws;                  // 51,380,224 B
  unsigned short* TB  = (unsigned short*)(ws + 51380224);     // 51,380,224 B
  signed char*    c1  = (signed char*)(ws + 102760448);       // 25,690,112 B
  unsigned short* BS  = (unsigned short*)(ws + 128450560);    //    393,216 B
  float*          BIG = (float*)(ws + 128843776);             //  1,048,576 B (PM / P1 / PVL)
  float*          PV  = (float*)(ws + 129892352);             //     32,768 B
  float*          MR  = (float*)(ws + 129925120);             //      8,192 B
  float*          outp = (float*)d_out;                       // fp32 NCHW

  float* P1  = BIG;   // [32][256] plane sums (layer1)
  float* PM  = BIG;   // [784][256] gemm block sums
  float* PVL = BIG;   // [1024][256] varT leaf sums
  float* M1 = MR;        float* R1 = MR + 256;
  float* M2 = MR + 512;  float* R2 = MR + 768;
  float* M3 = MR + 1024; float* R3 = MR + 1280;
  float* M4 = MR + 1536; float* R4 = MR + 1792;

  k_prepw <<<dim3(768),  dim3(256), 0, stream>>>(w1, w2, w3, BS);
  k_dwconv<<<dim3(8192), dim3(256), 0, stream>>>(x, wdw, a1, c1, P1);

  // BN1: fused mean partials, parallel np-ordered var, CR rsqrt
  k_cmb   <<<dim3(1),    dim3(256), 0, stream>>>(P1, M1);
  k_var1  <<<dim3(8192), dim3(256), 0, stream>>>(c1, a1, M1, PV);
  k_vcmb  <<<dim3(1),    dim3(256), 0, stream>>>(PV, R1);
  k_apply1<<<dim3(3136), dim3(256), 0, stream>>>(x, c1, a1, M1, R1, g1, b1, SB);

  // layer 2
  k_gemm  <<<dim3(784),  dim3(512), 0, stream>>>(SB, BS, a2, TB, PM);
  k_cmbG  <<<dim3(1),    dim3(256), 0, stream>>>(PM, M2);
  k_varT  <<<dim3(1024), dim3(256), 0, stream>>>(TB, M2, PVL);
  k_vcmbT <<<dim3(1),    dim3(256), 0, stream>>>(PVL, R2);
  k_apply2<<<dim3(3136), dim3(256), 0, stream>>>(x, c1, TB, a1,
                                                 M1, R1, g1, b1, M2, R2, g2, b2, SB);

  // layer 3
  k_gemm  <<<dim3(784),  dim3(512), 0, stream>>>(SB, BS + 65536, a3, TB, PM);
  k_cmbG  <<<dim3(1),    dim3(256), 0, stream>>>(PM, M3);
  k_varT  <<<dim3(1024), dim3(256), 0, stream>>>(TB, M3, PVL);
  k_vcmbT <<<dim3(1),    dim3(256), 0, stream>>>(PVL, R3);
  k_apply3<<<dim3(12544),dim3(256), 0, stream>>>(TB, M3, R3, g3, b3, SB);

  // layer 4
  k_gemm  <<<dim3(784),  dim3(512), 0, stream>>>(SB, BS + 131072, a4, TB, PM);
  k_cmbG  <<<dim3(1),    dim3(256), 0, stream>>>(PM, M4);
  k_varT  <<<dim3(1024), dim3(256), 0, stream>>>(TB, M4, PVL);
  k_vcmbT <<<dim3(1),    dim3(256), 0, stream>>>(PVL, R4);
  k_final <<<dim3(6272), dim3(256), 0, stream>>>(TB, M4, R4, g4, b4, outp);
}

// Round 15
// 449.810 us; speedup vs baseline: 1.7167x; 1.7167x over previous
//
#include <hip/hip_runtime.h>
#include <stdint.h>
#include <stddef.h>
#include <math.h>

#define HWSZ   3136        // 56*56
#define NPIX   100352      // 32*3136

typedef __attribute__((ext_vector_type(4))) float f32x4;
typedef __attribute__((ext_vector_type(8))) short bf16x8;
typedef __attribute__((ext_vector_type(8))) unsigned short u16x8;

__device__ __forceinline__ float bf2f(unsigned short u) {
  union { float f; unsigned int i; } v; v.i = ((unsigned int)u) << 16; return v.f;
}
__device__ __forceinline__ unsigned short f2bf(float f) {
  union { float f; unsigned int i; } v; v.f = f;
  return (unsigned short)((v.i + 0x7FFFu + ((v.i >> 16) & 1u)) >> 16);
}
__device__ __forceinline__ unsigned short sgnf_bf16(float v) {
  return (v > 0.f) ? 0x3F80u : ((v < 0.f) ? 0xBF80u : 0u);
}
__device__ __forceinline__ int isgn(float v) {
  return (v > 0.f) ? 1 : ((v < 0.f) ? -1 : 0);
}

// ---------------------------------------------------------------------------
// K0: weight prep: sign(w) as bf16, [o][c] layout
// ---------------------------------------------------------------------------
__global__ __launch_bounds__(256) void k_prepw(const float* __restrict__ w1,
    const float* __restrict__ w2, const float* __restrict__ w3,
    unsigned short* __restrict__ bs)
{
  int idx = blockIdx.x * 256 + threadIdx.x;
  int wsel = idx >> 16, rem = idx & 65535;
  const float* wp = (wsel == 0) ? w1 : ((wsel == 1) ? w2 : w3);
  float v = wp[rem];
  bs[idx] = sgnf_bf16(v);
}

// ---------------------------------------------------------------------------
// K1: depthwise 3x3 sign-conv -> c1 int8 + fused plane mean-partials.
// ---------------------------------------------------------------------------
__global__ __launch_bounds__(256) void k_dwconv(const float* __restrict__ x,
    const float* __restrict__ wdw, const float* __restrict__ a1,
    signed char* __restrict__ c1, float* __restrict__ P1)
{
  __shared__ float sp[58 * 60];    // row r = h+1, col = w+2
  __shared__ float rs[4];
  int bid = blockIdx.x;            // n*256 + c
  int c = bid & 255;
  int t = threadIdx.x;
  const float* xp = x + (size_t)bid * HWSZ;

  for (int i = t; i < 58 * 60; i += 256) sp[i] = 0.f;
  __syncthreads();
  for (int q = t; q < 784; q += 256) {
    int h = q / 14, w0 = (q - h * 14) * 4;
    f32x4 v = *(const f32x4*)(xp + h * 56 + w0);
    float* d = sp + (h + 1) * 60 + (w0 + 2);
    d[0] = (float)isgn(v[0]);
    d[1] = (float)isgn(v[1]);
    d[2] = (float)isgn(v[2]);
    d[3] = (float)isgn(v[3]);
  }
  float wsf[9];
  #pragma unroll
  for (int i = 0; i < 9; i++) wsf[i] = (float)isgn(wdw[c * 9 + i]);
  float av = a1[c];
  __syncthreads();

  float lsum = 0.f;
  signed char* outp = c1 + (size_t)bid * HWSZ;
  for (int q = t; q < 784; q += 256) {
    int h = q / 14, w0 = (q - h * 14) * 4;
    float win[3][8];
    #pragma unroll
    for (int r = 0; r < 3; r++) {
      const float* rowp = sp + (h + r) * 60 + w0;
      *(f32x4*)(&win[r][0]) = *(const f32x4*)rowp;
      *(f32x4*)(&win[r][4]) = *(const f32x4*)(rowp + 4);
    }
    unsigned int pk = 0;
    #pragma unroll
    for (int j = 0; j < 4; j++) {
      float acc = 0.f;
      #pragma unroll
      for (int r = 0; r < 3; r++) {
        acc = fmaf(win[r][j + 1], wsf[r * 3 + 0], acc);
        acc = fmaf(win[r][j + 2], wsf[r * 3 + 1], acc);
        acc = fmaf(win[r][j + 3], wsf[r * 3 + 2], acc);
      }
      int ia = (int)acc;
      pk |= ((unsigned int)(unsigned char)(signed char)ia) << (8 * j);
      lsum += (acc >= 0.f) ? acc : av * acc;       // exact quarter-ints
    }
    *(unsigned int*)(void*)(outp + h * 56 + w0) = pk;
  }
  for (int o = 32; o > 0; o >>= 1) lsum += __shfl_xor(lsum, o);
  if ((t & 63) == 0) rs[t >> 6] = lsum;
  __syncthreads();
  if (t == 0) P1[bid] = ((rs[0] + rs[1]) + (rs[2] + rs[3]));
}

// mean combine (layer1): seq over 32 plane sums (exact), /100352 f32
__global__ __launch_bounds__(256) void k_cmb(const float* __restrict__ P,
    float* __restrict__ M)
{
  int c = threadIdx.x;
  float acc = 0.f;
  for (int n = 0; n < 32; n++) acc = __fadd_rn(acc, P[n * 256 + c]);
  M[c] = __fdiv_rn(acc, 100352.0f);
}

// mean combine (gemm layers): seq over 784 block partials (exact)
__global__ __launch_bounds__(256) void k_cmbG(const float* __restrict__ PM,
    float* __restrict__ M)
{
  int c = threadIdx.x;
  float acc = 0.f;
  for (int b = 0; b < 784; b++) acc = __fadd_rn(acc, PM[(size_t)b * 256 + c]);
  M[c] = __fdiv_rn(acc, 100352.0f);
}

// ===========================================================================
// VARIANCE — bit-exact numpy float32 pairwise order, parallelized.
// ===========================================================================

// var1: one block per (n,c) plane (NCHW int8); 256 thr = 32 leaves x 8 accs
__global__ __launch_bounds__(256) void k_var1(const signed char* __restrict__ c1,
    const float* __restrict__ a1, const float* __restrict__ M,
    float* __restrict__ PV)
{
  __shared__ float rr[256];
  __shared__ float lsm[32];
  int bid = blockIdx.x;
  int c = bid & 255;
  int t = threadIdx.x;
  int lf = t >> 3, j = t & 7;
  const int base = (lf >> 2) * 392 + (lf & 3) * 96;
  const int nb = ((lf & 3) == 3) ? 13 : 12;
  const signed char* pl = c1 + (size_t)bid * HWSZ + base + j;
  float av = a1[c], m = M[c];
  float r;
  {
    float v = (float)(int)pl[0];
    float tt = (v >= 0.f) ? v : __fmul_rn(av, v);
    float d = __fsub_rn(tt, m);
    r = __fmul_rn(d, d);
  }
  for (int b = 1; b < nb; b++) {
    float v = (float)(int)pl[8 * b];
    float tt = (v >= 0.f) ? v : __fmul_rn(av, v);
    float d = __fsub_rn(tt, m);
    r = __fadd_rn(r, __fmul_rn(d, d));
  }
  rr[t] = r;
  __syncthreads();
  if (j == 0) {
    const float* q = rr + lf * 8;
    lsm[lf] = __fadd_rn(
        __fadd_rn(__fadd_rn(q[0], q[1]), __fadd_rn(q[2], q[3])),
        __fadd_rn(__fadd_rn(q[4], q[5]), __fadd_rn(q[6], q[7])));
  }
  __syncthreads();
  if (t == 0) {
    float ch[8];
    #pragma unroll
    for (int q8 = 0; q8 < 8; q8++)
      ch[q8] = __fadd_rn(__fadd_rn(lsm[q8 * 4], lsm[q8 * 4 + 1]),
                         __fadd_rn(lsm[q8 * 4 + 2], lsm[q8 * 4 + 3]));
    float s0 = __fadd_rn(ch[0], ch[1]), s1 = __fadd_rn(ch[2], ch[3]);
    float s2 = __fadd_rn(ch[4], ch[5]), s3 = __fadd_rn(ch[6], ch[7]);
    PV[bid] = __fadd_rn(__fadd_rn(s0, s1), __fadd_rn(s2, s3));
  }
}

// var combine (layer1): seq over n plane sums, /100352, CR f32 rsqrt
__global__ __launch_bounds__(256) void k_vcmb(const float* __restrict__ PV,
    float* __restrict__ R)
{
  int c = threadIdx.x;
  float acc = 0.f;
  for (int n = 0; n < 32; n++) acc = __fadd_rn(acc, PV[n * 256 + c]);
  float v = __fdiv_rn(acc, 100352.0f);
  R[c] = (float)(1.0 / sqrt((double)__fadd_rn(v, 1e-5f)));
}

// varT: one block per (n, leaf) (NHWC bf16); 256 thr = 256 channels
__global__ __launch_bounds__(256) void k_varT(const unsigned short* __restrict__ tb,
    const float* __restrict__ M, float* __restrict__ PVL)
{
  int n = blockIdx.x >> 5, lf = blockIdx.x & 31;
  int c = threadIdx.x;
  const int base = (lf >> 2) * 392 + (lf & 3) * 96;
  const int nb = ((lf & 3) == 3) ? 13 : 12;
  const unsigned short* pl = tb + ((size_t)n * HWSZ + base) * 256 + c;
  float m = M[c];
  float r[8];
  #pragma unroll
  for (int j = 0; j < 8; j++) {
    float d = __fsub_rn(bf2f(pl[(size_t)j * 256]), m);
    r[j] = __fmul_rn(d, d);
  }
  for (int b = 1; b < nb; b++) {
    #pragma unroll
    for (int j = 0; j < 8; j++) {
      float d = __fsub_rn(bf2f(pl[(size_t)(8 * b + j) * 256]), m);
      r[j] = __fadd_rn(r[j], __fmul_rn(d, d));
    }
  }
  float lv = __fadd_rn(
      __fadd_rn(__fadd_rn(r[0], r[1]), __fadd_rn(r[2], r[3])),
      __fadd_rn(__fadd_rn(r[4], r[5]), __fadd_rn(r[6], r[7])));
  PVL[(size_t)blockIdx.x * 256 + c] = lv;
}

// varT combine: exact tree over 32 leaves, seq over n, /100352, CR rsqrt
__global__ __launch_bounds__(256) void k_vcmbT(const float* __restrict__ PVL,
    float* __restrict__ R)
{
  int c = threadIdx.x;
  float acc = 0.f;
  for (int n = 0; n < 32; n++) {
    float ch[8];
    #pragma unroll
    for (int q = 0; q < 8; q++) {
      const float* p = PVL + ((size_t)(n * 32 + q * 4)) * 256 + c;
      ch[q] = __fadd_rn(__fadd_rn(p[0], p[256]), __fadd_rn(p[512], p[768]));
    }
    float s0 = __fadd_rn(ch[0], ch[1]), s1 = __fadd_rn(ch[2], ch[3]);
    float s2 = __fadd_rn(ch[4], ch[5]), s3 = __fadd_rn(ch[6], ch[7]);
    float plane = __fadd_rn(__fadd_rn(s0, s1), __fadd_rn(s2, s3));
    acc = __fadd_rn(acc, plane);
  }
  float v = __fdiv_rn(acc, 100352.0f);
  R[c] = (float)(1.0 / sqrt((double)__fadd_rn(v, 1e-5f)));
}

// ---------------------------------------------------------------------------
// K2: apply1: SB = sign( ((t1-m)*r)*g + b + x ). 4 px/thread, vectorized
// f32x4 x-loads + uint c1-loads; XOR block-swizzled LDS staging.
// ---------------------------------------------------------------------------
__global__ __launch_bounds__(256) void k_apply1(const float* __restrict__ x,
    const signed char* __restrict__ c1, const float* __restrict__ a1,
    const float* __restrict__ M1, const float* __restrict__ R1,
    const float* __restrict__ g1, const float* __restrict__ b1,
    unsigned short* __restrict__ s1)
{
  __shared__ __align__(16) unsigned short lb[32 * 264];
  int bid = blockIdx.x;
  int n = bid / 98, pb = bid % 98;
  int px0 = pb * 32;
  int t = threadIdx.x;

  int pxg = (t & 7) * 4, cb = t >> 3;
  #pragma unroll
  for (int j = 0; j < 8; j++) {
    int c = cb + j * 32;
    size_t gidx = ((size_t)(n * 256 + c)) * HWSZ + px0 + pxg;
    f32x4 xv = *(const f32x4*)(x + gidx);
    unsigned int cp = *(const unsigned int*)(const void*)(c1 + gidx);
    float av = a1[c];
    float m1 = M1[c], r1 = R1[c], gg1 = g1[c], bb1 = b1[c];
    #pragma unroll
    for (int e = 0; e < 4; e++) {
      int row = pxg + e;
      int idx = row * 264 + (c ^ (((row >> 2) & 7) << 3));
      float v = (float)(int)(signed char)(unsigned char)(cp >> (8 * e));
      float t1 = (v >= 0.f) ? v : __fmul_rn(av, v);
      float xn = __fmul_rn(__fsub_rn(t1, m1), r1);
      float bn = __fadd_rn(__fmul_rn(xn, gg1), bb1);
      float o1 = __fadd_rn(bn, xv[e]);
      lb[idx] = sgnf_bf16(o1);
    }
  }
  __syncthreads();
  unsigned short* sp = s1 + ((size_t)(n * HWSZ + px0)) * 256;
  for (int j = 0; j < 4; j++) {
    int f = j * 256 + t;
    int px = f >> 5, c16 = f & 31;
    int cs = (c16 ^ ((px >> 2) & 7)) * 8;
    *(u16x8*)(sp + px * 256 + c16 * 8) = *(const u16x8*)(lb + px * 264 + cs);
  }
}

// ---------------------------------------------------------------------------
// K4: apply2: SB = sign( bn2(t2) + (bn1(t1)+x) ). In-place swizzled LDS,
// 4 px/thread vectorized x/c1 loads. Slot (px,c) read+written by same thread.
// ---------------------------------------------------------------------------
__global__ __launch_bounds__(256) void k_apply2(const float* __restrict__ x,
    const signed char* __restrict__ c1, const unsigned short* __restrict__ t2,
    const float* __restrict__ a1,
    const float* __restrict__ M1, const float* __restrict__ R1,
    const float* __restrict__ g1, const float* __restrict__ b1,
    const float* __restrict__ M2, const float* __restrict__ R2,
    const float* __restrict__ g2, const float* __restrict__ b2,
    unsigned short* __restrict__ s2)
{
  __shared__ __align__(16) unsigned short lb[32 * 264];
  int bid = blockIdx.x;
  int n = bid / 98, pb = bid % 98;
  int px0 = pb * 32;
  int t = threadIdx.x;

  const unsigned short* tp = t2 + ((size_t)(n * HWSZ + px0)) * 256;
  for (int j = 0; j < 4; j++) {
    int f = j * 256 + t;
    int px = f >> 5, c16 = f & 31;
    int cs = (c16 ^ ((px >> 2) & 7)) * 8;
    *(u16x8*)(lb + px * 264 + cs) = *(const u16x8*)(tp + px * 256 + c16 * 8);
  }
  __syncthreads();

  int pxg = (t & 7) * 4, cb = t >> 3;
  #pragma unroll
  for (int j = 0; j < 8; j++) {
    int c = cb + j * 32;
    size_t gidx = ((size_t)(n * 256 + c)) * HWSZ + px0 + pxg;
    f32x4 xv = *(const f32x4*)(x + gidx);
    unsigned int cp = *(const unsigned int*)(const void*)(c1 + gidx);
    float av = a1[c];
    float m1 = M1[c], r1 = R1[c], gg1 = g1[c], bb1 = b1[c];
    float m2 = M2[c], r2 = R2[c], gg2 = g2[c], bb2 = b2[c];
    #pragma unroll
    for (int e = 0; e < 4; e++) {
      int row = pxg + e;
      int idx = row * 264 + (c ^ (((row >> 2) & 7) << 3));
      float v = (float)(int)(signed char)(unsigned char)(cp >> (8 * e));
      float t1 = (v >= 0.f) ? v : __fmul_rn(av, v);
      float xn1 = __fmul_rn(__fsub_rn(t1, m1), r1);
      float bn1v = __fadd_rn(__fmul_rn(xn1, gg1), bb1);
      float o1 = __fadd_rn(bn1v, xv[e]);
      float t2v = bf2f(lb[idx]);
      float xn2 = __fmul_rn(__fsub_rn(t2v, m2), r2);
      float bn2v = __fadd_rn(__fmul_rn(xn2, gg2), bb2);
      float o2 = __fadd_rn(bn2v, o1);
      lb[idx] = sgnf_bf16(o2);
    }
  }
  __syncthreads();
  unsigned short* sp = s2 + ((size_t)(n * HWSZ + px0)) * 256;
  for (int j = 0; j < 4; j++) {
    int f = j * 256 + t;
    int px = f >> 5, c16 = f & 31;
    int cs = (c16 ^ ((px >> 2) & 7)) * 8;
    *(u16x8*)(sp + px * 256 + c16 * 8) = *(const u16x8*)(lb + px * 264 + cs);
  }
}

// ---------------------------------------------------------------------------
// K6: apply3: SB = sign( bn3(t3) ), f32-replica, elementwise NHWC
// ---------------------------------------------------------------------------
__global__ __launch_bounds__(256) void k_apply3(const unsigned short* __restrict__ t3,
    const float* __restrict__ M3, const float* __restrict__ R3,
    const float* __restrict__ g3, const float* __restrict__ b3,
    unsigned short* __restrict__ s3)
{
  size_t idx = ((size_t)blockIdx.x * 256 + threadIdx.x) * 8;
  int c0 = (int)(idx & 255);
  u16x8 v = *(const u16x8*)(t3 + idx);
  u16x8 o;
  #pragma unroll
  for (int e = 0; e < 8; e++) {
    int c = c0 + e;
    float t = bf2f(v[e]);
    float xn = __fmul_rn(__fsub_rn(t, M3[c]), R3[c]);
    float bn = __fadd_rn(__fmul_rn(xn, g3[c]), b3[c]);
    o[e] = sgnf_bf16(bn);
  }
  *(u16x8*)(s3 + idx) = o;
}

// ---------------------------------------------------------------------------
// K8: final: out = bn4(t4), NHWC bf16 -> NCHW fp32. 16-px tile, [px][260]
// ---------------------------------------------------------------------------
__global__ __launch_bounds__(256) void k_final(const unsigned short* __restrict__ t4,
    const float* __restrict__ M4, const float* __restrict__ R4,
    const float* __restrict__ g4, const float* __restrict__ b4,
    float* __restrict__ outp)
{
  __shared__ __align__(16) float lt[16 * 260];
  int bid = blockIdx.x;
  int n = bid / 196, pb = bid % 196;
  int px0 = pb * 16;
  int t = threadIdx.x;

  const unsigned short* tp = t4 + ((size_t)(n * HWSZ + px0)) * 256;
  for (int j = 0; j < 2; j++) {
    int f = j * 256 + t;
    int px = f >> 5, c16 = f & 31;
    u16x8 v = *(const u16x8*)(tp + px * 256 + c16 * 8);
    f32x4 o0, o1;
    #pragma unroll
    for (int e = 0; e < 4; e++) {
      int c = c16 * 8 + e;
      float tv = bf2f(v[e]);
      float xn = __fmul_rn(__fsub_rn(tv, M4[c]), R4[c]);
      o0[e] = __fadd_rn(__fmul_rn(xn, g4[c]), b4[c]);
    }
    #pragma unroll
    for (int e = 0; e < 4; e++) {
      int c = c16 * 8 + 4 + e;
      float tv = bf2f(v[4 + e]);
      float xn = __fmul_rn(__fsub_rn(tv, M4[c]), R4[c]);
      o1[e] = __fadd_rn(__fmul_rn(xn, g4[c]), b4[c]);
    }
    *(f32x4*)(lt + px * 260 + c16 * 8) = o0;
    *(f32x4*)(lt + px * 260 + c16 * 8 + 4) = o1;
  }
  __syncthreads();
  for (int j = 0; j < 4; j++) {
    int f = j * 256 + t;
    int c = f >> 2, q = f & 3;
    f32x4 v;
    #pragma unroll
    for (int e = 0; e < 4; e++) v[e] = lt[(q * 4 + e) * 260 + c];
    *(f32x4*)(outp + ((size_t)(n * 256 + c)) * HWSZ + px0 + q * 4) = v;
  }
}

// ---------------------------------------------------------------------------
// K3/5/7: GEMM: TB = prelu(SB x BS^T), exact ints via bf16 MFMA.
// XOR-swizzled LDS (48KB -> 3 blocks/CU) + LDS-staged vectorized C-write
// + fused per-block column mean-partials (exact quarter-int f32 sums).
// NOTE: no min-waves hint — (512,6) capped VGPR at 40 and spilled acc
// to scratch (r14: FETCH+WRITE 476MB, 2.4x slowdown).
// ---------------------------------------------------------------------------
__global__ __launch_bounds__(512) void k_gemm(
    const unsigned short* __restrict__ sIn, const unsigned short* __restrict__ bsg,
    const float* __restrict__ aP, unsigned short* __restrict__ tOut,
    float* __restrict__ PM)
{
  __shared__ __align__(16) char smem[49152];
  unsigned short* As = (unsigned short*)smem;             // [128][64] swizzled
  unsigned short* Bs = (unsigned short*)(smem + 16384);   // [256][64] swizzled
  unsigned short* Cs = (unsigned short*)smem;             // [64][264] epilogue overlay
  float* red = (float*)(smem + 33792);                    // [8][32][8] (8KB)
  const int t = threadIdx.x;
  const int lane = t & 63;
  const int wid = t >> 6;
  const int wm = wid >> 2, wn = wid & 3;
  const int lr = lane & 15, lk = lane >> 4;
  const int pix0 = blockIdx.x * 128;
  const unsigned short* Ap = sIn + (size_t)pix0 * 256;

  f32x4 acc[4][4];
  #pragma unroll
  for (int i = 0; i < 4; i++)
    #pragma unroll
    for (int j = 0; j < 4; j++)
      acc[i][j] = (f32x4){0.f, 0.f, 0.f, 0.f};

  for (int kt = 0; kt < 4; kt++) {
    const int k0 = kt * 64;
    if (kt) __syncthreads();
    #pragma unroll
    for (int j = 0; j < 2; j++) {
      int idx = j * 512 + t;
      int row = idx >> 3, kc = idx & 7;
      u16x8 v = *(const u16x8*)(Ap + (size_t)row * 256 + k0 + kc * 8);
      *(u16x8*)(As + row * 64 + ((kc ^ (row & 7)) * 8)) = v;
    }
    #pragma unroll
    for (int j = 0; j < 4; j++) {
      int idx = j * 512 + t;
      int row = idx >> 3, kc = idx & 7;
      u16x8 v = *(const u16x8*)(bsg + (size_t)row * 256 + k0 + kc * 8);
      *(u16x8*)(Bs + row * 64 + ((kc ^ (row & 7)) * 8)) = v;
    }
    __syncthreads();
    #pragma unroll
    for (int h = 0; h < 2; h++) {
      bf16x8 af[4], bfr[4];
      #pragma unroll
      for (int mf = 0; mf < 4; mf++) {
        int row = wm * 64 + mf * 16 + lr;
        int ch = (h * 4 + lk) ^ (row & 7);
        af[mf] = *(const bf16x8*)(As + row * 64 + ch * 8);
      }
      #pragma unroll
      for (int nf = 0; nf < 4; nf++) {
        int nrow = wn * 64 + nf * 16 + lr;
        int ch = (h * 4 + lk) ^ (nrow & 7);
        bfr[nf] = *(const bf16x8*)(Bs + nrow * 64 + ch * 8);
      }
      #pragma unroll
      for (int mf = 0; mf < 4; mf++)
        #pragma unroll
        for (int nf = 0; nf < 4; nf++)
          acc[mf][nf] = __builtin_amdgcn_mfma_f32_16x16x32_bf16(
              af[mf], bfr[nf], acc[mf][nf], 0, 0, 0);
    }
  }

  // Epilogue: prelu -> Cs staging -> vectorized full-line stores + exact sums
  float lsum[8];
  #pragma unroll
  for (int e = 0; e < 8; e++) lsum[e] = 0.f;

  #pragma unroll
  for (int h = 0; h < 2; h++) {
    __syncthreads();
    if (wm == h) {
      #pragma unroll
      for (int nf = 0; nf < 4; nf++) {
        int col = wn * 64 + nf * 16 + lr;
        float av = aP[col];
        #pragma unroll
        for (int mf = 0; mf < 4; mf++) {
          #pragma unroll
          for (int r = 0; r < 4; r++) {
            int row = mf * 16 + lk * 4 + r;      // C/D: col=lane&15,row=(lane>>4)*4+r
            float u = acc[mf][nf][r];
            float tv = (u >= 0.f) ? u : __fmul_rn(av, u);   // exact quarter-ints
            Cs[row * 264 + col] = f2bf(tv);                 // lossless
          }
        }
      }
    }
    __syncthreads();
    #pragma unroll
    for (int j = 0; j < 4; j++) {
      int f = j * 512 + t;
      int row = f >> 5, c16 = f & 31;            // c16 == t&31, const per thread
      u16x8 v = *(const u16x8*)(Cs + row * 264 + c16 * 8);
      *(u16x8*)(tOut + ((size_t)(pix0 + h * 64 + row)) * 256 + c16 * 8) = v;
      #pragma unroll
      for (int e = 0; e < 8; e++)
        lsum[e] = __fadd_rn(lsum[e], bf2f(v[e]));           // exact, order-free
    }
  }
  #pragma unroll
  for (int e = 0; e < 8; e++)
    lsum[e] = __fadd_rn(lsum[e], __shfl_xor(lsum[e], 32));
  if (lane < 32) {
    #pragma unroll
    for (int e = 0; e < 8; e++) red[(wid * 32 + lane) * 8 + e] = lsum[e];
  }
  __syncthreads();
  if (t < 256) {
    int c16 = t >> 3, e = t & 7;
    float S = 0.f;
    #pragma unroll
    for (int w = 0; w < 8; w++)
      S = __fadd_rn(S, red[((w * 32 + c16) * 8 + e)]);
    PM[(size_t)blockIdx.x * 256 + t] = S;
  }
}

// ---------------------------------------------------------------------------
extern "C" void kernel_launch(void* const* d_in, const int* in_sizes, int n_in,
                              void* d_out, int out_size, void* d_ws, size_t ws_size,
                              hipStream_t stream)
{
  const float* x   = (const float*)d_in[0];
  const float* wdw = (const float*)d_in[1];
  const float* w1  = (const float*)d_in[2];
  const float* w2  = (const float*)d_in[3];
  const float* w3  = (const float*)d_in[4];
  const float* a1  = (const float*)d_in[5];
  const float* a2  = (const float*)d_in[6];
  const float* a3  = (const float*)d_in[7];
  const float* a4  = (const float*)d_in[8];
  const float* g1  = (const float*)d_in[9];
  const float* b1  = (const float*)d_in[10];
  const float* g2  = (const float*)d_in[11];
  const float* b2  = (const float*)d_in[12];
  const float* g3  = (const float*)d_in[13];
  const float* b3  = (const float*)d_in[14];
  const float* g4  = (const float*)d_in[15];
  const float* b4  = (const float*)d_in[16];

  char* ws = (char*)d_ws;
  unsigned short* SB  = (unsigned short*)ws;                  // 51,380,224 B
  unsigned short* TB  = (unsigned short*)(ws + 51380224);     // 51,380,224 B
  signed char*    c1  = (signed char*)(ws + 102760448);       // 25,690,112 B
  unsigned short* BS  = (unsigned short*)(ws + 128450560);    //    393,216 B
  float*          BIG = (float*)(ws + 128843776);             //  1,048,576 B (PM / P1 / PVL)
  float*          PV  = (float*)(ws + 129892352);             //     32,768 B
  float*          MR  = (float*)(ws + 129925120);             //      8,192 B
  float*          outp = (float*)d_out;                       // fp32 NCHW

  float* P1  = BIG;   // [32][256] plane sums (layer1)
  float* PM  = BIG;   // [784][256] gemm block sums
  float* PVL = BIG;   // [1024][256] varT leaf sums
  float* M1 = MR;        float* R1 = MR + 256;
  float* M2 = MR + 512;  float* R2 = MR + 768;
  float* M3 = MR + 1024; float* R3 = MR + 1280;
  float* M4 = MR + 1536; float* R4 = MR + 1792;

  k_prepw <<<dim3(768),  dim3(256), 0, stream>>>(w1, w2, w3, BS);
  k_dwconv<<<dim3(8192), dim3(256), 0, stream>>>(x, wdw, a1, c1, P1);

  // BN1: fused mean partials, parallel np-ordered var, CR rsqrt
  k_cmb   <<<dim3(1),    dim3(256), 0, stream>>>(P1, M1);
  k_var1  <<<dim3(8192), dim3(256), 0, stream>>>(c1, a1, M1, PV);
  k_vcmb  <<<dim3(1),    dim3(256), 0, stream>>>(PV, R1);
  k_apply1<<<dim3(3136), dim3(256), 0, stream>>>(x, c1, a1, M1, R1, g1, b1, SB);

  // layer 2
  k_gemm  <<<dim3(784),  dim3(512), 0, stream>>>(SB, BS, a2, TB, PM);
  k_cmbG  <<<dim3(1),    dim3(256), 0, stream>>>(PM, M2);
  k_varT  <<<dim3(1024), dim3(256), 0, stream>>>(TB, M2, PVL);
  k_vcmbT <<<dim3(1),    dim3(256), 0, stream>>>(PVL, R2);
  k_apply2<<<dim3(3136), dim3(256), 0, stream>>>(x, c1, TB, a1,
                                                 M1, R1, g1, b1, M2, R2, g2, b2, SB);

  // layer 3
  k_gemm  <<<dim3(784),  dim3(512), 0, stream>>>(SB, BS + 65536, a3, TB, PM);
  k_cmbG  <<<dim3(1),    dim3(256), 0, stream>>>(PM, M3);
  k_varT  <<<dim3(1024), dim3(256), 0, stream>>>(TB, M3, PVL);
  k_vcmbT <<<dim3(1),    dim3(256), 0, stream>>>(PVL, R3);
  k_apply3<<<dim3(12544),dim3(256), 0, stream>>>(TB, M3, R3, g3, b3, SB);

  // layer 4
  k_gemm  <<<dim3(784),  dim3(512), 0, stream>>>(SB, BS + 131072, a4, TB, PM);
  k_cmbG  <<<dim3(1),    dim3(256), 0, stream>>>(PM, M4);
  k_varT  <<<dim3(1024), dim3(256), 0, stream>>>(TB, M4, PVL);
  k_vcmbT <<<dim3(1),    dim3(256), 0, stream>>>(PVL, R4);
  k_final <<<dim3(6272), dim3(256), 0, stream>>>(TB, M4, R4, g4, b4, outp);
}